// Round 13
// baseline (98.553 us; speedup 1.0000x reference)
//
#include <hip/hip_runtime.h>
#include <math.h>

#define CN 128
#define SN 56
#define PXS 772                   // plane stride, ushorts (386 dw, %32 = 2)
#define SDW 386                   // plane stride, dwords
#define DYS 4696                  // gather dy step, ushorts = 6*PXS + 64
#define DXS 773                   // gather dx step, ushorts = PXS + 1
#define LOG2E 1.44269504088896341f

typedef float    fr4 __attribute__((ext_vector_type(4)));
typedef _Float16 hf8 __attribute__((ext_vector_type(8)));   // MFMA operand type
typedef __fp16   pkv __attribute__((ext_vector_type(2)));   // cvt_pkrtz result type

__device__ __forceinline__ int h2i(pkv h) {
    union { pkv h; int i; } u; u.h = h; return u.i;
}

// ---- Kernel A: Gaussian bank pre-swizzled into B-fragment order (f16) ----
// bank[c][ks][nt][lane][8 halfs]: element j = G^T[tap = nt*16+(lane&15)]
// [u = ks*32+(lane>>4)*8+j]; tap >= 36 -> 0.
__global__ void bank_kernel(const float* __restrict__ theta,
                            const float* __restrict__ p,
                            const float* __restrict__ sig,
                            const float* __restrict__ a,
                            unsigned short* __restrict__ bank) {
    int t = blockIdx.x * 256 + threadIdx.x;       // < 128*4*3*64 = 98304
    int lane = t & 63;
    int grp  = t >> 6;
    int nt = grp % 3;
    int ks = (grp / 3) & 3;
    int c  = grp / 12;
    int tap = nt * 16 + (lane & 15);
    int ub  = ks * 32 + (lane >> 4) * 8;
    hf8 v = {0,0,0,0,0,0,0,0};
    if (tap < 36) {
        int ky = tap / 6, kx = tap - ky * 6;
        float xv = -3.0f + 1.2f * ky;
        float yv = -3.0f + 1.2f * kx;
        #pragma unroll
        for (int j = 0; j < 8; ++j) {
            int pr = c * CN + ub + j;
            float th = theta[pr], pv = p[pr], sv = sig[pr], av = a[pr];
            float ct = __cosf(th), st = __sinf(th);
            float xr =  xv * ct + yv * st;
            float yr = -xv * st + yv * ct;
            float e  = -0.5f * (xr * xr / (pv * pv) + yr * yr / (sv * sv));
            float g  = (av / (2.0f * 3.14159265358979323846f * pv * sv))
                       * __builtin_amdgcn_exp2f(e * LOG2E);
            v[j] = (_Float16)g;
        }
    }
    ((hf8*)bank)[t] = v;
}

// ---- Main kernel: one block per (b, c, row-half h); 512 threads = 8 waves.
// Grid 512 = exactly 2 blocks/CU (55.6 KB LDS), zero dispatch tail.
// Four 7-row phases over the full 56-col width; P[36 taps][12 x 64 px] f16.
// Phase p>0 reuses the previous phase's last 5 P rows; the in-plane shift
// copy is partitioned by GEMM-tile ownership so NO barrier is needed between
// copy and GEMM (each wave overwrites only src dwords it itself copied;
// per-wave DS ordering makes the WAR safe). 7 barriers/block (was 10).
__global__ __launch_bounds__(512, 4) void divnorm_mfma(
        const float* __restrict__ x, const unsigned short* __restrict__ bank,
        const float* __restrict__ nI, const float* __restrict__ nU,
        const float* __restrict__ bias, float* __restrict__ out)
{
    __shared__ alignas(16) unsigned short SH[36 * PXS];   // 55584 B
    int*  SD  = (int*)SH;
    int2* SD2 = (int2*)SH;

    const int bid = blockIdx.x;
    const int h   = bid & 1;
    const int c   = (bid >> 1) & 127;
    const int b   = bid >> 8;
    const int tid = threadIdx.x;
    const int lane = tid & 63;
    const int wv   = tid >> 6;          // 0..7
    const int l15  = lane & 15;
    const int lg   = lane >> 4;

    // B-frags: 12 coalesced 16B loads from the pre-swizzled bank.
    hf8 Bf[3][4];
    {
        const hf8* bp = (const hf8*)bank + (size_t)c * 768 + lane;
        #pragma unroll
        for (int ks = 0; ks < 4; ++ks)
            #pragma unroll
            for (int nt = 0; nt < 3; ++nt)
                Bf[nt][ks] = bp[(ks * 3 + nt) * 64];
    }

    // Per-lane nI (A multipliers): u = ks*32 + lg*8 + j.
    float nIr[4][8];
    {
        const float* nc = nI + c * CN;
        #pragma unroll
        for (int ks = 0; ks < 4; ++ks) {
            const float4* q = (const float4*)(nc + ks * 32 + lg * 8);
            float4 q0 = q[0], q1 = q[1];
            nIr[ks][0] = q0.x; nIr[ks][1] = q0.y; nIr[ks][2] = q0.z; nIr[ks][3] = q0.w;
            nIr[ks][4] = q1.x; nIr[ks][5] = q1.y; nIr[ks][6] = q1.z; nIr[ks][7] = q1.w;
        }
    }

    const float* xc = x   + (size_t)(b * CN + c) * (SN * SN);
    float*       oc = out + (size_t)(b * CN + c) * (SN * SN);
    const float nUc = nU[c];
    const float bn  = __builtin_amdgcn_exp2f(nUc * __builtin_amdgcn_logf(bias[c]));

    // Scatter plane bases (dwords) for this lane's 3 taps (b64-aligned: SDW even).
    const int pof0 = l15 * SDW;
    const int pof1 = (16 + l15) * SDW;
    const int pof2 = (32 + l15) * SDW;

    // Gather geometry (once): 392 outputs, 1 per thread.
    const int oy = tid / 56;
    const int ox = tid - oy * 56;

    #pragma unroll 1
    for (int ph = 0; ph < 4; ++ph) {
        const int r0   = 28 * h + 7 * ph;
        const int r0m2 = r0 - 2;
        const int tb   = ph ? 20 : 0;        // first M-tile this phase

        // ---- Halo share: shift P rows 7..11 -> rows 0..4, barrier-free ----
        // Src dw [8t, 8t+8) of tile t (t in 28..47) copied by the SAME wave
        // that GEMM-writes tile t below; copy writes rows 0..4 (disjoint from
        // GEMM writes, rows 5..11). Only the post-gather barrier is needed.
        if (ph > 0) {
            __syncthreads();                 // prior gather reads done
            #pragma unroll
            for (int tt = 0; tt < 3; ++tt) {
                int t = 28 + wv + 8 * tt;    // this wave's src-range tiles
                if (t < 48) {
                    #pragma unroll
                    for (int it = 0; it < 3; ++it) {
                        int item = lane + 64 * it;          // < 144 = 36 pl x 4
                        if (item < 144) {
                            int pl = item >> 2;
                            int k  = item & 3;
                            SD2[pl * 193 + 4 * t - 112 + k] =
                                SD2[pl * 193 + 4 * t + k];
                        }
                    }
                }
            }
        }

        // ---- GEMM + transposed scatter (tile = tb + wv + 8i, tiles tb..47) ----
        int pidx = (tb + wv) * 16 + l15;     // px index; row = px>>6, col = px&63
        int prow = r0m2 + (pidx >> 6);
        int pcol = (pidx & 63) - 2;
        bool val = ((unsigned)prow < 56u) && ((unsigned)pcol < 56u);
        float xv = xc[val ? (prow * SN + pcol) : 0];

        #pragma unroll 2
        for (int tile = tb + wv; tile < 48; tile += 8) {
            float L = val ? __builtin_amdgcn_logf(xv) : -1e30f;   // OOB -> t=0

            // Prefetch next tile's x (dummy-clamped on last iteration).
            {
                int np   = pidx + 128;
                int nprw = r0m2 + (np >> 6);
                int npcc = (np & 63) - 2;
                val = ((unsigned)nprw < 56u) && ((unsigned)npcc < 56u);
                xv  = xc[val ? (nprw * SN + npcc) : 0];
                pidx = np;
            }

            fr4 a0 = {0.f,0.f,0.f,0.f}, a1 = {0.f,0.f,0.f,0.f}, a2 = {0.f,0.f,0.f,0.f};
            #pragma unroll
            for (int ks = 0; ks < 4; ++ks) {
                float t[8];
                #pragma unroll
                for (int j = 0; j < 8; ++j)
                    t[j] = __builtin_amdgcn_exp2f(nIr[ks][j] * L);
                union { pkv h[4]; hf8 v; } af;
                af.h[0] = __builtin_amdgcn_cvt_pkrtz(t[0], t[1]);
                af.h[1] = __builtin_amdgcn_cvt_pkrtz(t[2], t[3]);
                af.h[2] = __builtin_amdgcn_cvt_pkrtz(t[4], t[5]);
                af.h[3] = __builtin_amdgcn_cvt_pkrtz(t[6], t[7]);
                a0 = __builtin_amdgcn_mfma_f32_16x16x32_f16(af.v, Bf[0][ks], a0, 0, 0, 0);
                a1 = __builtin_amdgcn_mfma_f32_16x16x32_f16(af.v, Bf[1][ks], a1, 0, 0, 0);
                a2 = __builtin_amdgcn_mfma_f32_16x16x32_f16(af.v, Bf[2][ks], a2, 0, 0, 0);
            }

            // C (px = tile*16+lg*4+r, tap = nt*16+l15) -> P[tap][px], b64 stores.
            int pbd = tile * 8 + lg * 2;                  // dword px base (even)
            int2 v0, v1;
            v0.x = h2i(__builtin_amdgcn_cvt_pkrtz(a0[0], a0[1]));
            v0.y = h2i(__builtin_amdgcn_cvt_pkrtz(a0[2], a0[3]));
            v1.x = h2i(__builtin_amdgcn_cvt_pkrtz(a1[0], a1[1]));
            v1.y = h2i(__builtin_amdgcn_cvt_pkrtz(a1[2], a1[3]));
            *(int2*)&SD[pof0 + pbd] = v0;
            *(int2*)&SD[pof1 + pbd] = v1;
            if (l15 < 4) {                                // taps 32..35 only
                int2 v2;
                v2.x = h2i(__builtin_amdgcn_cvt_pkrtz(a2[0], a2[1]));
                v2.y = h2i(__builtin_amdgcn_cvt_pkrtz(a2[2], a2[3]));
                *(int2*)&SD[pof2 + pbd] = v2;
            }
        }
        __syncthreads();

        // ---- Gather: out = x^nU / (bias^nU + sum_tap P[tap][px(tap)]) ----
        if (tid < 7 * 56) {
            const unsigned short* pb = &SH[oy * 64 + ox];
            float s = 0.0f;
            #pragma unroll
            for (int dy = 0; dy < 6; ++dy)
                #pragma unroll
                for (int dx = 0; dx < 6; ++dx)
                    s += (float)(*(const _Float16*)&pb[dy * DYS + dx * DXS]);
            int y = r0 + oy;
            float xq  = xc[y * SN + ox];
            float num = __builtin_amdgcn_exp2f(nUc * __builtin_amdgcn_logf(xq));
            oc[y * SN + ox] = num / (bn + s);
        }
    }
}

extern "C" void kernel_launch(void* const* d_in, const int* in_sizes, int n_in,
                              void* d_out, int out_size, void* d_ws, size_t ws_size,
                              hipStream_t stream) {
    const float* x     = (const float*)d_in[0];
    const float* theta = (const float*)d_in[1];
    const float* p     = (const float*)d_in[2];
    const float* sig   = (const float*)d_in[3];
    const float* a     = (const float*)d_in[4];
    const float* nI    = (const float*)d_in[5];
    const float* nU    = (const float*)d_in[6];
    const float* bias  = (const float*)d_in[7];
    float* out = (float*)d_out;
    unsigned short* bank = (unsigned short*)d_ws;   // 128*768*8 halfs = 1.57 MB

    hipLaunchKernelGGL(bank_kernel, dim3(384), dim3(256), 0, stream,
                       theta, p, sig, a, bank);
    // (b, c, h) -> 2*128*2 = 512 blocks
    hipLaunchKernelGGL(divnorm_mfma, dim3(4 * CN), dim3(512), 0, stream,
                       x, bank, nI, nU, bias, out);
}

// Round 14
// 97.829 us; speedup vs baseline: 1.0074x; 1.0074x over previous
//
#include <hip/hip_runtime.h>
#include <math.h>

#define CN 128
#define SN 56
#define PXS 772                   // plane stride, ushorts (386 dw, %32 = 2)
#define SDW 386                   // plane stride, dwords
#define DYS 4696                  // gather dy step, ushorts = 6*PXS + 64
#define DXS 773                   // gather dx step, ushorts = PXS + 1
#define LOG2E 1.44269504088896341f

typedef float    fr4 __attribute__((ext_vector_type(4)));
typedef _Float16 hf8 __attribute__((ext_vector_type(8)));   // MFMA operand type
typedef __fp16   pkv __attribute__((ext_vector_type(2)));   // cvt_pkrtz result type

__device__ __forceinline__ int h2i(pkv h) {
    union { pkv h; int i; } u; u.h = h; return u.i;
}

// ---- Kernel A: Gaussian bank pre-swizzled into B-fragment order (f16) ----
// bank[c][ks][nt][lane][8 halfs]: element j = G^T[tap = nt*16+(lane&15)]
// [u = ks*32+(lane>>4)*8+j]; tap >= 36 -> 0.
__global__ void bank_kernel(const float* __restrict__ theta,
                            const float* __restrict__ p,
                            const float* __restrict__ sig,
                            const float* __restrict__ a,
                            unsigned short* __restrict__ bank) {
    int t = blockIdx.x * 256 + threadIdx.x;       // < 128*4*3*64 = 98304
    int lane = t & 63;
    int grp  = t >> 6;
    int nt = grp % 3;
    int ks = (grp / 3) & 3;
    int c  = grp / 12;
    int tap = nt * 16 + (lane & 15);
    int ub  = ks * 32 + (lane >> 4) * 8;
    hf8 v = {0,0,0,0,0,0,0,0};
    if (tap < 36) {
        int ky = tap / 6, kx = tap - ky * 6;
        float xv = -3.0f + 1.2f * ky;
        float yv = -3.0f + 1.2f * kx;
        #pragma unroll
        for (int j = 0; j < 8; ++j) {
            int pr = c * CN + ub + j;
            float th = theta[pr], pv = p[pr], sv = sig[pr], av = a[pr];
            float ct = __cosf(th), st = __sinf(th);
            float xr =  xv * ct + yv * st;
            float yr = -xv * st + yv * ct;
            float e  = -0.5f * (xr * xr / (pv * pv) + yr * yr / (sv * sv));
            float g  = (av / (2.0f * 3.14159265358979323846f * pv * sv))
                       * __builtin_amdgcn_exp2f(e * LOG2E);
            v[j] = (_Float16)g;
        }
    }
    ((hf8*)bank)[t] = v;
}

// ---- Main kernel: one block per (b, c, row-half h); 512 threads = 8 waves.
// Grid 512 = exactly 2 blocks/CU (55.6 KB LDS), zero dispatch tail.
// Four 7-row phases over the full 56-col width; P[36 taps][12 x 64 px] f16.
// Phase p>0 reuses the previous phase's last 5 P rows (barrier-free,
// ownership-partitioned shift copy). Per-phase tile stride is exactly 2
// plane rows -> column predicate hoisted, row/offset advance incremental.
__global__ __launch_bounds__(512, 4) void divnorm_mfma(
        const float* __restrict__ x, const unsigned short* __restrict__ bank,
        const float* __restrict__ nI, const float* __restrict__ nU,
        const float* __restrict__ bias, float* __restrict__ out)
{
    __shared__ alignas(16) unsigned short SH[36 * PXS];   // 55584 B
    int*  SD  = (int*)SH;
    int2* SD2 = (int2*)SH;

    const int bid = blockIdx.x;
    const int h   = bid & 1;
    const int c   = (bid >> 1) & 127;
    const int b   = bid >> 8;
    const int tid = threadIdx.x;
    const int lane = tid & 63;
    const int wv   = tid >> 6;          // 0..7
    const int l15  = lane & 15;
    const int lg   = lane >> 4;

    // B-frags: 12 coalesced 16B loads from the pre-swizzled bank.
    hf8 Bf[3][4];
    {
        const hf8* bp = (const hf8*)bank + (size_t)c * 768 + lane;
        #pragma unroll
        for (int ks = 0; ks < 4; ++ks)
            #pragma unroll
            for (int nt = 0; nt < 3; ++nt)
                Bf[nt][ks] = bp[(ks * 3 + nt) * 64];
    }

    // Per-lane nI (A multipliers): u = ks*32 + lg*8 + j.
    float nIr[4][8];
    {
        const float* nc = nI + c * CN;
        #pragma unroll
        for (int ks = 0; ks < 4; ++ks) {
            const float4* q = (const float4*)(nc + ks * 32 + lg * 8);
            float4 q0 = q[0], q1 = q[1];
            nIr[ks][0] = q0.x; nIr[ks][1] = q0.y; nIr[ks][2] = q0.z; nIr[ks][3] = q0.w;
            nIr[ks][4] = q1.x; nIr[ks][5] = q1.y; nIr[ks][6] = q1.z; nIr[ks][7] = q1.w;
        }
    }

    const float* xc = x   + (size_t)(b * CN + c) * (SN * SN);
    float*       oc = out + (size_t)(b * CN + c) * (SN * SN);
    const float nUc = nU[c];
    const float bn  = __builtin_amdgcn_exp2f(nUc * __builtin_amdgcn_logf(bias[c]));

    // Scatter plane bases (dwords) for this lane's 3 taps (b64-aligned: SDW even).
    const int pof0 = l15 * SDW;
    const int pof1 = (16 + l15) * SDW;
    const int pof2 = (32 + l15) * SDW;

    // Column geometry is phase-invariant for this lane (tile stride = 2 rows).
    const int colw = ((wv * 16 + l15) & 63) - 2;          // tb*16 keeps &63 (tb=20: 320&63=0? 320 = 5*64 -> 0) see below
    // NOTE: tb=20 -> first px = (20+wv)*16+l15 = 320 + wv*16 + l15; 320 % 64 = 0,
    // so (px & 63) is the same expression for both tb values.
    const bool colok = ((unsigned)colw < 56u);

    // Gather geometry (once): 392 outputs, 1 per thread.
    const int oy = tid / 56;
    const int ox = tid - oy * 56;

    #pragma unroll 1
    for (int ph = 0; ph < 4; ++ph) {
        const int r0   = 28 * h + 7 * ph;
        const int r0m2 = r0 - 2;
        const int tb   = ph ? 20 : 0;        // first M-tile this phase

        // ---- Halo share: shift P rows 7..11 -> rows 0..4, barrier-free ----
        // (see r13: src int2 [4t,4t+4) of tile t in 28..47 copied by the same
        // wave that GEMM-writes tile t; copy dst rows 0..4 disjoint from GEMM
        // writes rows 5..11; per-wave DS ordering makes the WAR safe.)
        if (ph > 0) {
            __syncthreads();                 // prior gather reads done
            #pragma unroll
            for (int tt = 0; tt < 3; ++tt) {
                int t = 28 + wv + 8 * tt;    // this wave's src-range tiles
                if (t < 48) {
                    #pragma unroll
                    for (int it = 0; it < 3; ++it) {
                        int item = lane + 64 * it;          // < 144 = 36 pl x 4
                        if (item < 144) {
                            int pl = item >> 2;
                            int k  = item & 3;
                            SD2[pl * 193 + 4 * t - 112 + k] =
                                SD2[pl * 193 + 4 * t + k];
                        }
                    }
                }
            }
        }

        // ---- GEMM + transposed scatter (tile = tb + wv + 8i, tiles tb..47) ----
        int prow = r0m2 + (((tb + wv) * 16 + l15) >> 6);
        int off  = prow * SN + colw;
        bool val = colok && ((unsigned)prow < 56u);
        float xv = xc[val ? off : 0];
        int pbd  = (tb + wv) * 8 + lg * 2;   // dword px base (even), += 64/iter

        #pragma unroll 1
        for (int tile = tb + wv; tile < 48; tile += 8) {
            float L = val ? __builtin_amdgcn_logf(xv) : -1e30f;   // OOB -> t=0

            // Prefetch next tile's x: advance exactly 2 rows.
            prow += 2;
            off  += 2 * SN;
            val = colok && ((unsigned)prow < 56u);
            xv  = xc[val ? off : 0];

            fr4 a0 = {0.f,0.f,0.f,0.f}, a1 = {0.f,0.f,0.f,0.f}, a2 = {0.f,0.f,0.f,0.f};
            #pragma unroll
            for (int ks = 0; ks < 4; ++ks) {
                float t[8];
                #pragma unroll
                for (int j = 0; j < 8; ++j)
                    t[j] = __builtin_amdgcn_exp2f(nIr[ks][j] * L);
                union { pkv h[4]; hf8 v; } af;
                af.h[0] = __builtin_amdgcn_cvt_pkrtz(t[0], t[1]);
                af.h[1] = __builtin_amdgcn_cvt_pkrtz(t[2], t[3]);
                af.h[2] = __builtin_amdgcn_cvt_pkrtz(t[4], t[5]);
                af.h[3] = __builtin_amdgcn_cvt_pkrtz(t[6], t[7]);
                a0 = __builtin_amdgcn_mfma_f32_16x16x32_f16(af.v, Bf[0][ks], a0, 0, 0, 0);
                a1 = __builtin_amdgcn_mfma_f32_16x16x32_f16(af.v, Bf[1][ks], a1, 0, 0, 0);
                a2 = __builtin_amdgcn_mfma_f32_16x16x32_f16(af.v, Bf[2][ks], a2, 0, 0, 0);
            }

            // C (px = tile*16+lg*4+r, tap = nt*16+l15) -> P[tap][px], b64 stores.
            int2 v0, v1;
            v0.x = h2i(__builtin_amdgcn_cvt_pkrtz(a0[0], a0[1]));
            v0.y = h2i(__builtin_amdgcn_cvt_pkrtz(a0[2], a0[3]));
            v1.x = h2i(__builtin_amdgcn_cvt_pkrtz(a1[0], a1[1]));
            v1.y = h2i(__builtin_amdgcn_cvt_pkrtz(a1[2], a1[3]));
            *(int2*)&SD[pof0 + pbd] = v0;
            *(int2*)&SD[pof1 + pbd] = v1;
            if (l15 < 4) {                                // taps 32..35 only
                int2 v2;
                v2.x = h2i(__builtin_amdgcn_cvt_pkrtz(a2[0], a2[1]));
                v2.y = h2i(__builtin_amdgcn_cvt_pkrtz(a2[2], a2[3]));
                *(int2*)&SD[pof2 + pbd] = v2;
            }
            pbd += 64;
        }
        __syncthreads();

        // ---- Gather: out = x^nU / (bias^nU + sum_tap P[tap][px(tap)]) ----
        if (tid < 7 * 56) {
            const unsigned short* pb = &SH[oy * 64 + ox];
            float s = 0.0f;
            #pragma unroll
            for (int dy = 0; dy < 6; ++dy)
                #pragma unroll
                for (int dx = 0; dx < 6; ++dx)
                    s += (float)(*(const _Float16*)&pb[dy * DYS + dx * DXS]);
            int y = r0 + oy;
            float xq  = xc[y * SN + ox];
            float num = __builtin_amdgcn_exp2f(nUc * __builtin_amdgcn_logf(xq));
            oc[y * SN + ox] = num / (bn + s);
        }
    }
}

extern "C" void kernel_launch(void* const* d_in, const int* in_sizes, int n_in,
                              void* d_out, int out_size, void* d_ws, size_t ws_size,
                              hipStream_t stream) {
    const float* x     = (const float*)d_in[0];
    const float* theta = (const float*)d_in[1];
    const float* p     = (const float*)d_in[2];
    const float* sig   = (const float*)d_in[3];
    const float* a     = (const float*)d_in[4];
    const float* nI    = (const float*)d_in[5];
    const float* nU    = (const float*)d_in[6];
    const float* bias  = (const float*)d_in[7];
    float* out = (float*)d_out;
    unsigned short* bank = (unsigned short*)d_ws;   // 128*768*8 halfs = 1.57 MB

    hipLaunchKernelGGL(bank_kernel, dim3(384), dim3(256), 0, stream,
                       theta, p, sig, a, bank);
    // (b, c, h) -> 2*128*2 = 512 blocks
    hipLaunchKernelGGL(divnorm_mfma, dim3(4 * CN), dim3(512), 0, stream,
                       x, bank, nI, nU, bias, out);
}